// Round 7
// baseline (304.500 us; speedup 1.0000x reference)
//
#include <hip/hip_runtime.h>
#include <stdint.h>

// B=131072 rows, K=IN=256, N=OUT=256.
// temp = act @ weight.T (exact int32, |t| < 2^24); r = max|temp|;
// bw = ceil(log2(max(r,1))) (0 if r<=1); shift = bw-7;
// shift>0 ? round_shift(temp,shift) clipped to [-127,127] : int8-wrap(temp)
// exp_out = exp_in + weight_exp + max(shift,0)  (int16 semantics)
// Harness reads d_out as INT32: [B*N values, 1 exp scalar].
//
// R7: k1 = single-barrier GEMM (full-K A-tile in LDS, B direct from L2-hot
// bf16 weight, no B staging) -> temp in d_ws + global max. k2 = streaming
// quantize d_ws -> d_out (nt stores). GEMM was latency/barrier-bound, not
// HBM-bound (R2: 1.4 TB/s @ 95us) -- this removes 7 of 8 barriers and lifts
// occupancy 3->4 blocks/CU.

#define M_ROWS 131072
#define NK 256
#define BM 64
#define AKP 264    // padded LDS row stride (bf16 elems) = 528 B (banks shift by 4/row)

typedef __attribute__((ext_vector_type(8))) short bf16x8;
typedef __attribute__((ext_vector_type(4))) float f32x4;
typedef __attribute__((ext_vector_type(4))) float fv4;
typedef __attribute__((ext_vector_type(4))) int iv4;
typedef __attribute__((ext_vector_type(4))) unsigned int u32x4;
typedef __attribute__((ext_vector_type(4))) unsigned short us4;

__device__ __forceinline__ uint32_t pack_bf16(float a, float b) {
  // exact for integer-valued floats |v| <= 255
  return (__float_as_uint(a) >> 16) | (__float_as_uint(b) & 0xFFFF0000u);
}

// Prepass: weight fp32 -> bf16 (65536 elems; 128 KB, stays L2-resident)
__global__ void wconv(const float* __restrict__ w, unsigned short* __restrict__ wb) {
  const int i = blockIdx.x * 256 + threadIdx.x;
  const fv4 f = ((const fv4*)w)[i];
  us4 o;
  o.x = (unsigned short)(__float_as_uint(f.x) >> 16);
  o.y = (unsigned short)(__float_as_uint(f.y) >> 16);
  o.z = (unsigned short)(__float_as_uint(f.z) >> 16);
  o.w = (unsigned short)(__float_as_uint(f.w) >> 16);
  ((us4*)wb)[i] = o;
}

// k1: GEMM over full K in one LDS stage; B fragments straight from global
// (L2-hot). Writes int32 temp (regular stores -> LLC) + global abs-max.
// 256 threads = 4 waves; block tile 64 x 256 (full N); wave w: cols w*64..+63.
__global__ __launch_bounds__(256) void gemm_store_max(
    const float* __restrict__ act,           // [M,256] int-valued fp32
    const unsigned short* __restrict__ wgtb, // [256,256] bf16, L2-resident
    int* __restrict__ temp,                  // [M,256] int32 (d_ws)
    int* __restrict__ gmax)                  // [1] global abs-max (pre-zeroed)
{
  __shared__ __align__(16) short As[BM * AKP];   // 33792 B
  __shared__ int smax;

  const int tid = threadIdx.x;
  if (tid == 0) smax = 0;

  const int bm   = blockIdx.x * BM;
  const int lane = tid & 63;
  const int wave = tid >> 6;
  const int lm   = lane & 15;
  const int lk   = lane >> 4;
  const int wn   = wave * 64;

  // Stage whole A tile: 64 rows x 256 k = 2048 chunks of 8 fp32 -> 8 bf16.
  // Thread tid, j=0..7: chunk c = tid + j*256; row = c>>5, seg = c&31.
  {
    const int arow = tid >> 5;          // 0..7 (+8 per j)
    const int aseg = tid & 31;          // 0..31
    const float* pbase = act + (size_t)(bm + arow) * NK + aseg * 8;
#pragma unroll
    for (int j = 0; j < 8; ++j) {
      const float* p = pbase + (size_t)(j * 8) * NK;
      const fv4 f0 = *(const fv4*)p;
      const fv4 f1 = *((const fv4*)p + 1);
      uint32_t pk[4];
      pk[0] = pack_bf16(f0.x, f0.y); pk[1] = pack_bf16(f0.z, f0.w);
      pk[2] = pack_bf16(f1.x, f1.y); pk[3] = pack_bf16(f1.z, f1.w);
      *(u32x4*)&As[(arow + j * 8) * AKP + aseg * 8] = *(const u32x4*)pk;
    }
  }
  __syncthreads();   // the only barrier

  f32x4 acc[4][4] = {};

  // 8 k-steps of 32; B fragment: lane reads wgtb[n = wn+ni*16+lm][kk + lk*8]
  const unsigned short* bbase = wgtb + (size_t)(wn + lm) * NK + lk * 8;
#pragma unroll
  for (int k8 = 0; k8 < 8; ++k8) {
    const int kk = k8 * 32;
    bf16x8 af[4];
    u32x4 bf[4];
#pragma unroll
    for (int ni = 0; ni < 4; ++ni)
      bf[ni] = *(const u32x4*)(bbase + (size_t)(ni * 16) * NK + kk);
#pragma unroll
    for (int mi = 0; mi < 4; ++mi)
      af[mi] = *(const bf16x8*)&As[(mi * 16 + lm) * AKP + kk + lk * 8];
#pragma unroll
    for (int mi = 0; mi < 4; ++mi)
#pragma unroll
      for (int ni = 0; ni < 4; ++ni)
        acc[mi][ni] = __builtin_amdgcn_mfma_f32_16x16x32_bf16(
            af[mi], *(const bf16x8*)&bf[ni], acc[mi][ni], 0, 0, 0);
  }

  // Epilogue: C/D layout col = lane&15, row = (lane>>4)*4 + reg  [m89]
  int imax = 0;
#pragma unroll
  for (int mi = 0; mi < 4; ++mi)
#pragma unroll
    for (int ni = 0; ni < 4; ++ni)
#pragma unroll
      for (int r = 0; r < 4; ++r) {
        const int iv = (int)acc[mi][ni][r];
        const int m = bm + mi * 16 + lk * 4 + r;
        const int n = wn + ni * 16 + lm;
        temp[(size_t)m * NK + n] = iv;    // regular store -> LLC-dirty
        const int a = iv < 0 ? -iv : iv;
        imax = a > imax ? a : imax;
      }
#pragma unroll
  for (int off = 32; off; off >>= 1) {
    const int o = __shfl_xor(imax, off, 64);
    imax = o > imax ? o : imax;
  }
  if (lane == 0) atomicMax(&smax, imax);
  __syncthreads();
  if (tid == 0) atomicMax(gmax, smax);
}

// k2: streaming quantize temp (d_ws, LLC-hot) -> out (d_out, nt stores).
__global__ __launch_bounds__(256) void quant_stream(
    const int* __restrict__ temp, int* __restrict__ out,
    const int* __restrict__ gmax,
    const int* __restrict__ exp_in, const int* __restrict__ wexp)
{
  const int r = *gmax;
  const int bw = (r <= 1) ? 0 : (32 - __clz(r - 1));   // ceil(log2(r))
  const int shift = bw - 7;
  const bool pos = shift > 0;
  const int s = shift < 1 ? 1 : shift;

  const int total4 = (M_ROWS * NK) / 4;   // 8388608
  const iv4* pin = (const iv4*)temp;
  iv4* pout = (iv4*)out;
  const int idx = blockIdx.x * blockDim.x + threadIdx.x;
  const int stride = gridDim.x * blockDim.x;

  for (int i = idx; i < total4; i += stride) {
    const iv4 t = pin[i];
    iv4 o;
#pragma unroll
    for (int j = 0; j < 4; ++j) {
      const int ti = t[j];
      int q;
      if (pos) {
        const int rt = ti >> s;                       // floor(t / 2^s)
        const int dec = (ti - (rt << s)) >> (s - 1);  // {0,1}
        q = rt + dec;
        q = q > 127 ? 127 : (q < -127 ? -127 : q);
      } else {
        q = (int)(signed char)(ti & 0xFF);            // int8 wrap
      }
      o[j] = q;
    }
    __builtin_nontemporal_store(o, &pout[i]);
  }

  if (idx == 0) {
    const int e = exp_in[0] + wexp[0] + (pos ? shift : 0);
    out[(size_t)M_ROWS * NK] = (int)(short)e;
  }
}

extern "C" void kernel_launch(void* const* d_in, const int* in_sizes, int n_in,
                              void* d_out, int out_size, void* d_ws, size_t ws_size,
                              hipStream_t stream) {
  const float* act   = (const float*)d_in[0];
  const int* exp_in  = (const int*)d_in[1];
  const float* wgt   = (const float*)d_in[2];
  const int* wexp    = (const int*)d_in[3];

  int* gmax          = (int*)d_ws;
  unsigned short* wb = (unsigned short*)((char*)d_ws + 4096);        // 128 KB
  int* temp          = (int*)((char*)d_ws + (1 << 20));              // 134 MB

  (void)hipMemsetAsync(d_ws, 0, sizeof(int), stream);
  wconv<<<dim3(64), dim3(256), 0, stream>>>(wgt, wb);
  gemm_store_max<<<dim3(M_ROWS / BM), dim3(256), 0, stream>>>(act, wb, temp, gmax);
  quant_stream<<<dim3(4096), dim3(256), 0, stream>>>(temp, (int*)d_out, gmax,
                                                     exp_in, wexp);
}